// Round 11
// baseline (96.147 us; speedup 1.0000x reference)
//
#include <hip/hip_runtime.h>
#include <hip/hip_bf16.h>

#define NTHREADS 512
#define N_ATOMS  1024
#define HIDDEN   64
#define SEGCAP   192     // per-wave queue entries (survivors ~65 +- 8, 16-sigma margin)
#define W2OFF    2176    // W1 = 34*64 floats
#define W3OFF    6272    // + W2 = 64*64
#define WTOT     10368   // + W3 = 64*64

// 8 atoms per block (1024 blocks, 512 threads), one WAVE per atom.
// H-weights fix: ALL MLP weights (41.5 KB) staged into LDS once per block,
// amortized over 8 atoms -> per-CU weight traffic cut 8x (was 41.5 KB
// through L1/L2 PER ATOM in every previous variant -- the invariant cost).
//  - neighbors staged as packed float4 (x,y,z,tsign) once per block (R10).
//  - per wave: 16 ballot sweeps; survivors sign-packed +/-d into a per-wave
//    LDS queue (no atomics); pad to x4 with d=100 (exp underflows to 0).
//  - drain: lane = (slot 0..3, rbf 0..15), 1 exp feeds both species accs;
//    shfl_xor(16,32) combine.
//  - MLP: shuffle-broadcast (R9/R10-proven), weights from LDS (stride-1,
//    2-way bank aliasing = free).  2 barriers total.
__global__ __launch_bounds__(NTHREADS) void LocalFeatureEncoder_40063454937486_kernel(
    const float* __restrict__ pos,    // [B,N,3]
    const int*   __restrict__ types,  // [B,N]
    const float* __restrict__ W1,     // [34,64]
    const float* __restrict__ b1,     // [64]
    const float* __restrict__ W2,     // [64,64]
    const float* __restrict__ b2,     // [64]
    const float* __restrict__ W3,     // [64,64]
    const float* __restrict__ b3,     // [64]
    float*       __restrict__ out)    // [B,N,64]
{
    const int tid  = threadIdx.x;
    const int lane = tid & 63;
    const int wav  = tid >> 6;                 // 0..7
    const int a    = blockIdx.x * 8 + wav;     // this wave's atom (b*N + i)
    const int bidx = blockIdx.x >> 7;          // 128 blocks per batch
    const int i    = a & (N_ATOMS - 1);

    __shared__ float4 sp[N_ATOMS];             // packed (x, y, z, tsign)  16 KB
    __shared__ float  sw[WTOT];                // W1|W2|W3                 41.5 KB
    __shared__ float  qv[8 * SEGCAP];          // per-wave +/-d queues      6 KB

    const float* pf   = pos + (size_t)bidx * (N_ATOMS * 3);
    const int*   typb = types + (size_t)bidx * N_ATOMS;

    // ---- stage neighbors (threads 0..255) + all weights (all threads) ----
    if (tid < 256) {
        const float4 p0 = *(const float4*)(pf + tid * 12);
        const float4 p1 = *(const float4*)(pf + tid * 12 + 4);
        const float4 p2 = *(const float4*)(pf + tid * 12 + 8);
        const int4   tv = *(const int4*)(typb + tid * 4);

        const float px[4] = {p0.x, p0.w, p1.z, p2.y};
        const float py[4] = {p0.y, p1.x, p1.w, p2.z};
        const float pz[4] = {p0.z, p1.y, p2.x, p2.w};
        const int   tj[4] = {tv.x, tv.y, tv.z, tv.w};
#pragma unroll
        for (int q = 0; q < 4; ++q)
            sp[tid * 4 + q] = make_float4(px[q], py[q], pz[q],
                                          (tj[q] == 0) ? 1.0f : -1.0f);
    }
    {   // W1: 544 float4, W2/W3: 1024 float4 each -> 2592 float4 over 512 thr
        for (int v = tid; v < 544; v += NTHREADS)
            *(float4*)&sw[v * 4] = *(const float4*)(W1 + v * 4);
        for (int v = tid; v < 1024; v += NTHREADS) {
            *(float4*)&sw[W2OFF + v * 4] = *(const float4*)(W2 + v * 4);
            *(float4*)&sw[W3OFF + v * 4] = *(const float4*)(W3 + v * 4);
        }
    }
    __syncthreads();

    const float4 self = sp[i];
    const float xi = self.x, yi = self.y, zi = self.z;

    // ---- sweeps + per-wave compaction (sign-packed +/-d) ----
    float* seg = &qv[wav * SEGCAP];
    int base = 0;                              // wave-uniform running count
#pragma unroll
    for (int s = 0; s < N_ATOMS / 64; ++s) {
        const int j = lane + s * 64;
        const float4 nb = sp[j];               // one ds_read_b128
        const float dx = xi - nb.x;
        const float dy = yi - nb.y;
        const float dz = zi - nb.z;
        const float sq = dx * dx + dy * dy + dz * dz;
        const bool pred = (j != i) && (sq < 6.25f);

        const unsigned long long mask = __ballot(pred);
        if (pred) {
            const float d = sqrtf(sq);
            const int idx = base + (int)__popcll(mask & ((1ull << lane) - 1ull));
            seg[idx] = (nb.w > 0.0f) ? d : -d; // sign encodes species
        }
        base += (int)__popcll(mask);
    }
    // pad to a multiple of 4 with d=100 (exp underflows to exactly 0)
    const int npad = (base + 3) & ~3;
    if (lane < npad - base) seg[base + lane] = 100.0f;
    __syncthreads();                           // queues + nothing else pending

    // ---- drain: lane = (slot 0..3, rbf r = lane&15) ----
    float acc0 = 0.0f, acc1 = 0.0f;
    {
        const int   slot = lane >> 4;
        const int   r    = lane & 15;
        const float c    = (float)r * (2.5f / 15.0f);
        for (int e = slot; e < npad; e += 4) {
            const float v   = seg[e];
            const float d   = fabsf(v);
            const float x   = d * 0.4f;        // d / 2.5
            const float x3  = x * x * x;
            const float cutv = 1.0f + x3 * (-10.0f + x * (15.0f - 6.0f * x));
            const float diff = d - c;
            const float ex   = __expf(diff * diff * -36.0f);  // 1/w^2 = 36
            acc0 += ex * ((v > 0.0f) ? cutv : 0.0f);
            acc1 += ex * ((v > 0.0f) ? 0.0f : cutv);
        }
    }
    acc0 += __shfl_xor(acc0, 16, 64);
    acc0 += __shfl_xor(acc0, 32, 64);
    acc1 += __shfl_xor(acc1, 16, 64);
    acc1 += __shfl_xor(acc1, 32, 64);
    // every lane in {r, r+16, r+32, r+48} holds full env[r][0/1]

    // ---- MLP 34 -> 64 -> 64 -> 64, shuffle-broadcast, weights from LDS ----
    const int t  = lane;                       // output unit this lane owns
    const int ti = (self.w < 0.0f) ? 1 : 0;    // own atom type (wave-uniform)

    float h1 = b1[t] + sw[ti * HIDDEN + t];    // onehot contribution
#pragma unroll
    for (int r = 0; r < 16; ++r) {
        h1 += __shfl(acc0, r, 64) * sw[(2 + 2 * r + 0) * HIDDEN + t];
        h1 += __shfl(acc1, r, 64) * sw[(2 + 2 * r + 1) * HIDDEN + t];
    }
    h1 = h1 / (1.0f + __expf(-h1));

    float h2 = b2[t];
#pragma unroll
    for (int k = 0; k < HIDDEN; ++k)
        h2 += __shfl(h1, k, 64) * sw[W2OFF + k * HIDDEN + t];
    h2 = h2 / (1.0f + __expf(-h2));

    float o = b3[t];
#pragma unroll
    for (int k = 0; k < HIDDEN; ++k)
        o += __shfl(h2, k, 64) * sw[W3OFF + k * HIDDEN + t];
    out[(size_t)a * HIDDEN + t] = o;
}

extern "C" void kernel_launch(void* const* d_in, const int* in_sizes, int n_in,
                              void* d_out, int out_size, void* d_ws, size_t ws_size,
                              hipStream_t stream) {
    const float* pos   = (const float*)d_in[0];
    const int*   types = (const int*)d_in[1];
    const float* W1    = (const float*)d_in[2];
    const float* b1    = (const float*)d_in[3];
    const float* W2    = (const float*)d_in[4];
    const float* b2    = (const float*)d_in[5];
    const float* W3    = (const float*)d_in[6];
    const float* b3    = (const float*)d_in[7];
    float*       out   = (float*)d_out;

    const int BN = in_sizes[1];                // B*N = 8192

    LocalFeatureEncoder_40063454937486_kernel<<<BN / 8, NTHREADS, 0, stream>>>(
        pos, types, W1, b1, W2, b2, W3, b3, out);
}